// Round 2
// baseline (94.665 us; speedup 1.0000x reference)
//
#include <hip/hip_runtime.h>

typedef __attribute__((ext_vector_type(4))) int i32x4;

#define HDIM 16
#define MDIM 2048
#define NDIM 2048
#define KDIM 128

// ---------------------------------------------------------------------------
// Pack int32 (values 0..126) -> int8. Each thread handles 16 elements:
// 4x 16B loads -> 1x 16B store.
// ---------------------------------------------------------------------------
__global__ void pack_i32_to_i8(const int* __restrict__ src,
                               unsigned char* __restrict__ dst,
                               int n_threads) {
    int t = blockIdx.x * blockDim.x + threadIdx.x;
    if (t >= n_threads) return;
    const i32x4* s = reinterpret_cast<const i32x4*>(src) + (size_t)t * 4;
    i32x4 v0 = s[0], v1 = s[1], v2 = s[2], v3 = s[3];
    i32x4 o;
    o.x = (v0.x & 255) | ((v0.y & 255) << 8) | ((v0.z & 255) << 16) | ((v0.w & 255) << 24);
    o.y = (v1.x & 255) | ((v1.y & 255) << 8) | ((v1.z & 255) << 16) | ((v1.w & 255) << 24);
    o.z = (v2.x & 255) | ((v2.y & 255) << 8) | ((v2.z & 255) << 16) | ((v2.w & 255) << 24);
    o.w = (v3.x & 255) | ((v3.y & 255) << 8) | ((v3.z & 255) << 16) | ((v3.w & 255) << 24);
    reinterpret_cast<i32x4*>(dst)[t] = o;
}

// ---------------------------------------------------------------------------
// Batched i8 GEMM: C[h] = A[h] (M x K) * B[h]^T (N x K, K contiguous).
// Block: 128x128 tile, 256 threads = 4 waves in 2x2; wave computes 64x64
// via 4x4 fragments of v_mfma_i32_16x16x64_i8, K = 2 steps of 64.
// Fused epilogue: c = clamp(rint(acc * (sA[m]/sO[m]) * sB[n]), -127, 127),
// stored as FLOAT32 (harness reads the whole output buffer as float32).
// ---------------------------------------------------------------------------
__global__ __launch_bounds__(256)
void gemm_i8_fused(const unsigned char* __restrict__ A8,
                   const unsigned char* __restrict__ B8,
                   const float* __restrict__ sA,
                   const float* __restrict__ sB,
                   const float* __restrict__ sO,
                   float* __restrict__ out) {
    const int h  = blockIdx.z;
    const int bm = blockIdx.y * 128;
    const int bn = blockIdx.x * 128;
    const int tid  = threadIdx.x;
    const int wave = tid >> 6;
    const int lane = tid & 63;
    const int wm = (wave >> 1) * 64;   // wave row offset in block tile
    const int wn = (wave & 1) * 64;    // wave col offset
    const int fr = lane & 15;          // row-in-16-group for A/B loads; out col
    const int kg = lane >> 4;          // 0..3 k-group

    const unsigned char* Ah = A8 + (size_t)h * MDIM * KDIM;
    const unsigned char* Bh = B8 + (size_t)h * NDIM * KDIM;

    i32x4 acc[4][4];
#pragma unroll
    for (int mi = 0; mi < 4; ++mi)
#pragma unroll
        for (int ni = 0; ni < 4; ++ni)
            acc[mi][ni] = (i32x4){0, 0, 0, 0};

#pragma unroll
    for (int ks = 0; ks < 2; ++ks) {
        const int kb = ks * 64 + kg * 16;   // this lane's 16-byte K chunk
        i32x4 af[4], bf[4];
#pragma unroll
        for (int mi = 0; mi < 4; ++mi)
            af[mi] = *reinterpret_cast<const i32x4*>(
                Ah + (size_t)(bm + wm + mi * 16 + fr) * KDIM + kb);
#pragma unroll
        for (int ni = 0; ni < 4; ++ni)
            bf[ni] = *reinterpret_cast<const i32x4*>(
                Bh + (size_t)(bn + wn + ni * 16 + fr) * KDIM + kb);
#pragma unroll
        for (int mi = 0; mi < 4; ++mi)
#pragma unroll
            for (int ni = 0; ni < 4; ++ni)
                acc[mi][ni] = __builtin_amdgcn_mfma_i32_16x16x64_i8(
                    af[mi], bf[ni], acc[mi][ni], 0, 0, 0);
    }

    // Epilogue. C/D layout: col = lane&15, row = (lane>>4)*4 + reg.
    const float* sAh = sA + h * MDIM;
    const float* sBh = sB + h * NDIM;
    const float* sOh = sO + h * MDIM;

    float sbv[4];
#pragma unroll
    for (int ni = 0; ni < 4; ++ni)
        sbv[ni] = sBh[bn + wn + ni * 16 + fr];

#pragma unroll
    for (int mi = 0; mi < 4; ++mi) {
#pragma unroll
        for (int r = 0; r < 4; ++r) {
            const int m = bm + wm + mi * 16 + kg * 4 + r;
            const float sm = sAh[m] / sOh[m];  // matches reference op order
            float* orow = out + ((size_t)h * MDIM + m) * NDIM + bn + wn + fr;
#pragma unroll
            for (int ni = 0; ni < 4; ++ni) {
                float c = (float)acc[mi][ni][r] * (sm * sbv[ni]);
                float rv = rintf(c);                 // RNE == np.round
                rv = fminf(fmaxf(rv, -127.0f), 127.0f);
                orow[ni * 16] = rv;                  // float32 store
            }
        }
    }
}

// ---------------------------------------------------------------------------
// Output 1: scale_out passthrough as float32 (exact).
// ---------------------------------------------------------------------------
__global__ void tail_scale_out(const float* __restrict__ sO,
                               float* __restrict__ out, int n) {
    int i = blockIdx.x * blockDim.x + threadIdx.x;
    if (i < n) out[i] = sO[i];
}

extern "C" void kernel_launch(void* const* d_in, const int* in_sizes, int n_in,
                              void* d_out, int out_size, void* d_ws, size_t ws_size,
                              hipStream_t stream) {
    const int*   A  = (const int*)d_in[0];
    const int*   B  = (const int*)d_in[1];
    const float* sA = (const float*)d_in[2];
    const float* sB = (const float*)d_in[3];
    const float* sO = (const float*)d_in[4];
    float* out = (float*)d_out;

    unsigned char* A8 = (unsigned char*)d_ws;
    unsigned char* B8 = A8 + (size_t)HDIM * MDIM * KDIM;

    const int nA = HDIM * MDIM * KDIM;       // 4,194,304 elements
    const int packThreads = nA / 16;         // 262,144
    pack_i32_to_i8<<<packThreads / 256, 256, 0, stream>>>(A, A8, packThreads);
    pack_i32_to_i8<<<packThreads / 256, 256, 0, stream>>>(B, B8, packThreads);

    dim3 grid(NDIM / 128, MDIM / 128, HDIM);
    gemm_i8_fused<<<grid, 256, 0, stream>>>(A8, B8, sA, sB, sO, out);

    const int nTail = HDIM * MDIM;           // 32,768
    tail_scale_out<<<nTail / 256, 256, 0, stream>>>(
        sO, out + (size_t)HDIM * MDIM * NDIM, nTail);
}